// Round 17
// baseline (537.711 us; speedup 1.0000x reference)
//
#include <hip/hip_runtime.h>

typedef unsigned int u32;
typedef unsigned short u16;

#define NB 32
#define N0V 2048
#define FEATV 1036
#define EDGESV (NB*N0V*16)   // 1048576
#define KK1 410
#define KK2 82
#define KK3 17
#define NN1 (NB*N0V)   // 65536
#define NN2 (NB*KK1)   // 13120
#define NN3 (NB*KK2)   // 2624
#define NN4 (NB*KK3)   // 544
#define KSTEP1 33      // ceil(1036/32)
#define KSTEP2 4       // 128/32
#define ESTR 32768     // per-graph edge region stride

typedef __bf16 bf16x8 __attribute__((ext_vector_type(8)));
typedef float f32x4 __attribute__((ext_vector_type(4)));

__device__ inline u16 f2bf(float f){
  u32 u = __float_as_uint(f);
  u32 r = (u + 0x7FFFu + ((u >> 16) & 1u)) >> 16;   // RNE
  return (u16)r;
}
__device__ inline float bf2f(u16 h){ return __uint_as_float(((u32)h) << 16); }
__device__ inline float dec_ord(u32 u){
  u32 bits = (u & 0x80000000u) ? (u ^ 0x80000000u) : ~u;
  return __uint_as_float(bits);
}
__device__ inline u16 bfbits(__bf16 b){ union{__bf16 f; u16 u;} c; c.f=b; return c.u; }
__device__ inline void cvt4c(float4 v, ushort4& h, ushort4& l){
  __bf16 h0=(__bf16)v.x, h1=(__bf16)v.y, h2=(__bf16)v.z, h3=(__bf16)v.w;
  float r0=v.x-(float)h0, r1=v.y-(float)h1, r2=v.z-(float)h2, r3=v.w-(float)h3;
  h.x=bfbits(h0); h.y=bfbits(h1); h.z=bfbits(h2); h.w=bfbits(h3);
  l.x=bfbits((__bf16)r0); l.y=bfbits((__bf16)r1);
  l.z=bfbits((__bf16)r2); l.w=bfbits((__bf16)r3);
}
__device__ inline void gload_lds16(const void* g, void* l){
  __builtin_amdgcn_global_load_lds(
      (const __attribute__((address_space(1))) unsigned int*)g,
      (__attribute__((address_space(3))) unsigned int*)l, 16, 0, 0);
}

// ---------------- tiny init ---------------------------------------------------
__global__ void init_kernel(u32* mx){
  if (threadIdx.x < 12) mx[threadIdx.x] = 0;
}
__global__ void fill0(int* p, int n){
  int i = blockIdx.x*256 + threadIdx.x;
  if (i < n) p[i] = 0;
}

// ---------------- column max of x[:, :12] (vectorized) -------------------------
__global__ void colmax_kernel(const float* __restrict__ x, u32* mx){
  __shared__ float sm[256];
  int t = threadIdx.x;
  int r = blockIdx.x*256 + t;          // grid 256 x 256 = NN1
  const float4* p = (const float4*)(x + (size_t)r*FEATV);
  float4 v0 = p[0], v1 = p[1], v2 = p[2];
  float m[12] = {v0.x,v0.y,v0.z,v0.w, v1.x,v1.y,v1.z,v1.w, v2.x,v2.y,v2.z,v2.w};
  for (int j=0;j<12;j++){
    sm[t] = m[j]; __syncthreads();
    for (int off=128; off>0; off>>=1){ if (t<off) sm[t]=fmaxf(sm[t],sm[t+off]); __syncthreads(); }
    if (t==0){
      u32 b = __float_as_uint(sm[0]);
      u32 u = (b & 0x80000000u) ? ~b : (b | 0x80000000u);
      atomicMax(&mx[j], u);
    }
    __syncthreads();
  }
}

// ------- build tiled B^T images for all 3 stages --------------------------------
__global__ void wprep_all(const float* __restrict__ W1l, const float* __restrict__ W1r,
                          const float* __restrict__ W2l, const float* __restrict__ W2r,
                          const float* __restrict__ W3l, const float* __restrict__ W3r,
                          const u32* __restrict__ mxo,
                          u16* __restrict__ B1h, u16* __restrict__ B1l,
                          u16* __restrict__ B2h, u16* __restrict__ B2l,
                          u16* __restrict__ B3h, u16* __restrict__ B3l){
  int idx = blockIdx.x*256 + threadIdx.x;
  const float *Wl, *Wr; u16 *oh, *ol; int K, o, scale12;
  if (idx < KSTEP1*8192){ Wl=W1l; Wr=W1r; oh=B1h; ol=B1l; K=FEATV; o=idx; scale12=1; }
  else if (idx < (KSTEP1+KSTEP2)*8192){ Wl=W2l; Wr=W2r; oh=B2h; ol=B2l; K=128; o=idx-KSTEP1*8192; scale12=0; }
  else if (idx < (KSTEP1+2*KSTEP2)*8192){ Wl=W3l; Wr=W3r; oh=B3h; ol=B3l; K=128; o=idx-(KSTEP1+KSTEP2)*8192; scale12=0; }
  else return;
  int kt = o >> 13, r13 = o & 8191;
  int khg = r13 >> 11, n = (r13 >> 3) & 255, kk8 = r13 & 7;
  int k = (kt << 5) + khg*8 + kk8;
  float v = 0.f;
  if (k < K) v = (n < 128) ? Wl[(size_t)k*128 + n] : Wr[(size_t)k*128 + (n-128)];
  if (scale12 && k < 12) v /= dec_ord(mxo[k]);
  u16 h = f2bf(v);
  oh[o] = h;
  ol[o] = f2bf(v - bf2f(h));
}

// ------- wide CSR: hist / per-graph scan / scatter (filter chain via inv1,inv2) -
__global__ void histf(const int* __restrict__ src, const int* __restrict__ dst,
                      const int* __restrict__ inv1, const int* __restrict__ inv2,
                      int np1, int nperOut, int* __restrict__ deg){
  int e = blockIdx.x*256 + threadIdx.x;
  if (e >= EDGESV) return;
  int s = src[e], d = dst[e];
  int g = d >> 11;
  int ls, ld;
  if (inv1){
    ls = inv1[s]; ld = inv1[d];
    if ((ls | ld) < 0) return;
    if (inv2){
      ls = inv2[g*np1 + ls]; ld = inv2[g*np1 + ld];
      if ((ls | ld) < 0) return;
    }
  } else { ld = d & 2047; }
  atomicAdd(&deg[g*nperOut + ld], 1);
}

__launch_bounds__(1024)
__global__ void scank(const int* __restrict__ deg, int nper,
                      int* __restrict__ rps, int* __restrict__ cur){
  __shared__ int part[1024];
  int g = blockIdx.x, t = threadIdx.x;
  int chunk = (nper + 1023) >> 10;
  int c0 = t*chunk, ss = 0;
  for (int u = 0; u < chunk; ++u){ int i = c0+u; if (i < nper) ss += deg[g*nper + i]; }
  part[t] = ss; __syncthreads();
  for (int off = 1; off < 1024; off <<= 1){
    int v = (t >= off) ? part[t-off] : 0;
    __syncthreads();
    part[t] += v;
    __syncthreads();
  }
  int run = part[t] - ss;
  for (int u = 0; u < chunk; ++u){
    int i = c0+u;
    if (i < nper){
      int pos = g*ESTR + run;
      rps[g*nper + i] = pos;
      cur[g*nper + i] = pos;
      run += deg[g*nper + i];
    }
  }
}

__global__ void scatf(const int* __restrict__ src, const int* __restrict__ dst,
                      const int* __restrict__ inv1, const int* __restrict__ inv2,
                      int np1, int nperOut, int* __restrict__ cur, int* __restrict__ adj){
  int e = blockIdx.x*256 + threadIdx.x;
  if (e >= EDGESV) return;
  int s = src[e], d = dst[e];
  int g = d >> 11;
  int ls, ld;
  if (inv1){
    ls = inv1[s]; ld = inv1[d];
    if ((ls | ld) < 0) return;
    if (inv2){
      ls = inv2[g*np1 + ls]; ld = inv2[g*np1 + ld];
      if ((ls | ld) < 0) return;
    }
  } else { ls = s & 2047; ld = d & 2047; }
  int p = atomicAdd(&cur[g*nperOut + ld], 1);
  adj[p] = ls;   // local src id
}

// ------- R3-structure pure GEMM (A+B LDS dbuf, counted vmcnt, 1 barrier) --------
__launch_bounds__(256, 2)
__global__ void gemm_kernel(const float* __restrict__ A, int lda,
                            int Kvalid, int Ksteps,
                            const u16* __restrict__ Bth, const u16* __restrict__ Btl,
                            float* __restrict__ hl, float* __restrict__ hr){
  __shared__ __align__(16) u16 Ah[2][2048];
  __shared__ __align__(16) u16 Al[2][2048];
  __shared__ __align__(16) u16 Bh[2][8192];
  __shared__ __align__(16) u16 Bl[2][8192];
  int tid = threadIdx.x;
  int row0 = blockIdx.x * 64;
  int w = tid >> 6, lane = tid & 63;
  int lr = lane & 15, kh = lane >> 4;

  int p0i = tid, p1i = tid + 256;
  int kg0 = p0i >> 7, rw0 = (p0i & 127) >> 1, hf0 = p0i & 1;
  int kg1 = p1i >> 7, rw1 = (p1i & 127) >> 1, hf1 = p1i & 1;
  int coff0 = kg0*8 + hf0*4, coff1 = kg1*8 + hf1*4;
  const float* pA0 = A + (size_t)(row0 + rw0)*lda + coff0;
  const float* pA1 = A + (size_t)(row0 + rw1)*lda + coff1;
  int wi0 = kg0*512 + rw0*8 + hf0*4;
  int wi1 = kg1*512 + rw1*8 + hf1*4;

  f32x4 acc[4][4];
  #pragma unroll
  for (int i=0;i<4;i++)
    #pragma unroll
    for (int j=0;j<4;j++) acc[i][j] = (f32x4){0.f,0.f,0.f,0.f};

  float4 z4 = make_float4(0.f,0.f,0.f,0.f);

#define LOADA(KT, V0, V1) { int k0_ = (KT)<<5; \
    V0 = (k0_ + coff0 < Kvalid) ? *(const float4*)(pA0 + k0_) : z4; \
    V1 = (k0_ + coff1 < Kvalid) ? *(const float4*)(pA1 + k0_) : z4; }

#define ISSUEB(KT, BUF) { size_t tb_ = (size_t)(KT)*8192; \
    _Pragma("unroll") \
    for (int j_=0;j_<4;j_++){ int o_ = j_*2048 + w*512; \
      gload_lds16(Bth + tb_ + o_ + lane*8, &Bh[BUF][o_]); \
      gload_lds16(Btl + tb_ + o_ + lane*8, &Bl[BUF][o_]); } }

#define CVTWRITE(V0, V1, BUF) { ushort4 h_, l_; \
    cvt4c(V0, h_, l_); *(ushort4*)&Ah[BUF][wi0] = h_; *(ushort4*)&Al[BUF][wi0] = l_; \
    cvt4c(V1, h_, l_); *(ushort4*)&Ah[BUF][wi1] = h_; *(ushort4*)&Al[BUF][wi1] = l_; }

  // ---- prologue ----
  float4 a0, a1, pp0, pp1;
  LOADA(0, a0, a1);
  ISSUEB(0, 0);
  LOADA(1, pp0, pp1);
  CVTWRITE(a0, a1, 0);
  asm volatile("s_waitcnt lgkmcnt(0)" ::: "memory");
  asm volatile("s_waitcnt vmcnt(2)" ::: "memory");
  __builtin_amdgcn_s_barrier();

  for (int kt = 0; kt < Ksteps; ++kt){
    int cur = kt & 1, nxt = cur ^ 1;
    if (kt+1 < Ksteps) ISSUEB(kt+1, nxt);
    float4 n0 = z4, n1 = z4;
    if (kt+2 < Ksteps) LOADA(kt+2, n0, n1);
    if (kt+2 < Ksteps)      asm volatile("s_waitcnt vmcnt(12)" ::: "memory");
    else if (kt+1 < Ksteps) asm volatile("s_waitcnt vmcnt(10)" ::: "memory");
    else                    asm volatile("s_waitcnt vmcnt(0)"  ::: "memory");

    bf16x8 fah[4], fal[4], fbh[4], fbl[4];
    #pragma unroll
    for (int mi=0;mi<4;mi++){
      int idx = kh*512 + (mi*16 + lr)*8;
      fah[mi] = *(const bf16x8*)&Ah[cur][idx];
      fal[mi] = *(const bf16x8*)&Al[cur][idx];
    }
    #pragma unroll
    for (int ni=0;ni<4;ni++){
      int idx = kh*2048 + (w*64 + ni*16 + lr)*8;
      fbh[ni] = *(const bf16x8*)&Bh[cur][idx];
      fbl[ni] = *(const bf16x8*)&Bl[cur][idx];
    }
    if (kt+1 < Ksteps) CVTWRITE(pp0, pp1, nxt);
    asm volatile("s_waitcnt lgkmcnt(0)" ::: "memory");
    __builtin_amdgcn_sched_barrier(0);
    __builtin_amdgcn_s_setprio(1);
    #pragma unroll
    for (int mi=0;mi<4;mi++)
      #pragma unroll
      for (int ni=0;ni<4;ni++){
        acc[mi][ni] = __builtin_amdgcn_mfma_f32_16x16x32_bf16(fah[mi], fbh[ni], acc[mi][ni], 0,0,0);
        acc[mi][ni] = __builtin_amdgcn_mfma_f32_16x16x32_bf16(fah[mi], fbl[ni], acc[mi][ni], 0,0,0);
        acc[mi][ni] = __builtin_amdgcn_mfma_f32_16x16x32_bf16(fal[mi], fbh[ni], acc[mi][ni], 0,0,0);
      }
    __builtin_amdgcn_s_setprio(0);
    pp0 = n0; pp1 = n1;
    __builtin_amdgcn_s_barrier();
  }
#undef LOADA
#undef ISSUEB
#undef CVTWRITE
  // epilogue: split C cols 0..127 -> hl, 128..255 -> hr
  float* dst = (w < 2) ? hl : hr;
  #pragma unroll
  for (int mi=0;mi<4;mi++)
    #pragma unroll
    for (int j=0;j<4;j++){
      int row = row0 + mi*16 + kh*4 + j;
      #pragma unroll
      for (int ni=0;ni<4;ni++){
        int ch = (w*64 + ni*16 + lr) & 127;
        dst[(size_t)row*128 + ch] = acc[mi][ni][j];
      }
    }
}

// -------- stage-1 SAGE finalize, 64-col half pass (L2-resident gather) ----------
// 4 nodes per wave, 16 lanes x float4 = 64 cols. XCD-affine graph mapping.
__global__ void convfin_half(const float* __restrict__ hl, const float* __restrict__ hr,
                             const int* __restrict__ rps, const int* __restrict__ rpd,
                             const int* __restrict__ adj, const float* __restrict__ bl,
                             float* __restrict__ xout, int c0){
  int b = blockIdx.x, t = threadIdx.x;
  int xcd = b & 7, idx = b >> 3;
  int g = xcd + 8*(idx >> 7);          // 128 blocks per graph, graphs {xcd,+8,+16,+24}
  int slot = idx & 127;
  int wv = t >> 6, lane = t & 63;
  int sub = lane >> 4, l16 = lane & 15;
  int i = slot*16 + wv*4 + sub;        // node within graph
  int gbase = g*N0V;
  int gi = gbase + i;
  int s = rps[gi], d = rpd[gi];
  const int* ap = adj + s;
  float4 a = make_float4(0.f,0.f,0.f,0.f);
  int e = 0;
  for (; e + 8 <= d; e += 8){
    int j0=ap[e],j1=ap[e+1],j2=ap[e+2],j3=ap[e+3];
    int j4=ap[e+4],j5=ap[e+5],j6=ap[e+6],j7=ap[e+7];
    float4 v0 = *(const float4*)(hl + (size_t)(gbase+j0)*128 + c0 + l16*4);
    float4 v1 = *(const float4*)(hl + (size_t)(gbase+j1)*128 + c0 + l16*4);
    float4 v2 = *(const float4*)(hl + (size_t)(gbase+j2)*128 + c0 + l16*4);
    float4 v3 = *(const float4*)(hl + (size_t)(gbase+j3)*128 + c0 + l16*4);
    float4 v4 = *(const float4*)(hl + (size_t)(gbase+j4)*128 + c0 + l16*4);
    float4 v5 = *(const float4*)(hl + (size_t)(gbase+j5)*128 + c0 + l16*4);
    float4 v6 = *(const float4*)(hl + (size_t)(gbase+j6)*128 + c0 + l16*4);
    float4 v7 = *(const float4*)(hl + (size_t)(gbase+j7)*128 + c0 + l16*4);
    a.x += v0.x+v1.x+v2.x+v3.x+v4.x+v5.x+v6.x+v7.x;
    a.y += v0.y+v1.y+v2.y+v3.y+v4.y+v5.y+v6.y+v7.y;
    a.z += v0.z+v1.z+v2.z+v3.z+v4.z+v5.z+v6.z+v7.z;
    a.w += v0.w+v1.w+v2.w+v3.w+v4.w+v5.w+v6.w+v7.w;
  }
  for (; e < d; ++e){
    float4 hj = *(const float4*)(hl + (size_t)(gbase + ap[e])*128 + c0 + l16*4);
    a.x += hj.x; a.y += hj.y; a.z += hj.z; a.w += hj.w;
  }
  float invc = 1.0f / fmaxf((float)d, 1.0f);
  float4 hrv = *(const float4*)(hr + (size_t)gi*128 + c0 + l16*4);
  float4 bb = *(const float4*)(bl + c0 + l16*4);
  float4 o;
  o.x = fmaxf(a.x*invc + bb.x + hrv.x, 0.f);
  o.y = fmaxf(a.y*invc + bb.y + hrv.y, 0.f);
  o.z = fmaxf(a.z*invc + bb.z + hrv.z, 0.f);
  o.w = fmaxf(a.w*invc + bb.w + hrv.w, 0.f);
  *(float4*)(xout + (size_t)gi*128 + c0 + l16*4) = o;
}

// -------- stage-1 score GEMV (wave-per-2-nodes, x1 streaming) -------------------
__global__ void hscgemv(const float* __restrict__ x1, const float* __restrict__ Wp,
                        float* __restrict__ hsc){
  int idx = blockIdx.x*256 + threadIdx.x;
  int wv = idx >> 6, lane = idx & 63;
  int sub = lane >> 5, l32 = lane & 31;
  int node = wv*2 + sub;
  float4 xv = *(const float4*)(x1 + (size_t)node*128 + l32*4);
  float4 wp = *(const float4*)(Wp + l32*4);
  float v = xv.x*wp.x + xv.y*wp.y + xv.z*wp.z + xv.w*wp.w;
  #pragma unroll
  for (int m = 16; m > 0; m >>= 1) v += __shfl_xor(v, m);
  if (l32 == 0) hsc[node] = v;
}

// -------- SAGE finalize + score GEMV (stages 2/3): batch-8 neighbor prefetch ----
__global__ void convfin_w(const float* __restrict__ hl, const float* __restrict__ hr,
                          const int* __restrict__ rps,
                          const int* __restrict__ rpd, const int* __restrict__ adj,
                          const float* __restrict__ bl, const float* __restrict__ Wp,
                          float* __restrict__ xout, float* __restrict__ hsc,
                          int nper, int bpg){
  int b = blockIdx.x, t = threadIdx.x;
  int g = b / bpg, slot = b - g*bpg;
  int wv = t >> 6, lane = t & 63;
  int sub = lane >> 5, l32 = lane & 31;
  int i = slot*8 + wv*2 + sub;
  if (i >= nper) return;
  int gbase = g*nper;
  int gi = gbase + i;
  int s = rps[gi], d = rpd[gi];
  const int* ap = adj + s;
  float4 a = make_float4(0.f,0.f,0.f,0.f);
  int e = 0;
  for (; e + 8 <= d; e += 8){
    int j0=ap[e],j1=ap[e+1],j2=ap[e+2],j3=ap[e+3];
    int j4=ap[e+4],j5=ap[e+5],j6=ap[e+6],j7=ap[e+7];
    float4 v0 = *(const float4*)(hl + (size_t)(gbase+j0)*128 + l32*4);
    float4 v1 = *(const float4*)(hl + (size_t)(gbase+j1)*128 + l32*4);
    float4 v2 = *(const float4*)(hl + (size_t)(gbase+j2)*128 + l32*4);
    float4 v3 = *(const float4*)(hl + (size_t)(gbase+j3)*128 + l32*4);
    float4 v4 = *(const float4*)(hl + (size_t)(gbase+j4)*128 + l32*4);
    float4 v5 = *(const float4*)(hl + (size_t)(gbase+j5)*128 + l32*4);
    float4 v6 = *(const float4*)(hl + (size_t)(gbase+j6)*128 + l32*4);
    float4 v7 = *(const float4*)(hl + (size_t)(gbase+j7)*128 + l32*4);
    a.x += v0.x+v1.x+v2.x+v3.x+v4.x+v5.x+v6.x+v7.x;
    a.y += v0.y+v1.y+v2.y+v3.y+v4.y+v5.y+v6.y+v7.y;
    a.z += v0.z+v1.z+v2.z+v3.z+v4.z+v5.z+v6.z+v7.z;
    a.w += v0.w+v1.w+v2.w+v3.w+v4.w+v5.w+v6.w+v7.w;
  }
  for (; e < d; ++e){
    float4 hj = *(const float4*)(hl + (size_t)(gbase + ap[e])*128 + l32*4);
    a.x += hj.x; a.y += hj.y; a.z += hj.z; a.w += hj.w;
  }
  float invc = 1.0f / fmaxf((float)d, 1.0f);
  float4 hrv = *(const float4*)(hr + (size_t)gi*128 + l32*4);
  float4 bb = *(const float4*)(bl + l32*4);
  float4 o;
  o.x = fmaxf(a.x*invc + bb.x + hrv.x, 0.f);
  o.y = fmaxf(a.y*invc + bb.y + hrv.y, 0.f);
  o.z = fmaxf(a.z*invc + bb.z + hrv.z, 0.f);
  o.w = fmaxf(a.w*invc + bb.w + hrv.w, 0.f);
  *(float4*)(xout + (size_t)gi*128 + l32*4) = o;
  float4 wp = *(const float4*)(Wp + l32*4);
  float v = o.x*wp.x + o.y*wp.y + o.z*wp.z + o.w*wp.w;
  #pragma unroll
  for (int m = 16; m > 0; m >>= 1) v += __shfl_xor(v, m);
  if (l32 == 0) hsc[gi] = v;
}

// -------- GCN score (2D grid: y=graph) -> order-mapped keys ---------------------
__global__ void scoreagg_w(const float* __restrict__ hsc, const int* __restrict__ rps,
                           const int* __restrict__ rpd, const int* __restrict__ adj,
                           const float* __restrict__ bp, int nper,
                           u32* __restrict__ su){
  int g = blockIdx.y;
  int i = blockIdx.x*256 + threadIdx.x;
  if (i >= nper) return;
  int gbase = g*nper;
  int gi = gbase + i;
  float di = 1.0f + (float)rpd[gi];
  float a = hsc[gi] / di;
  float rdi = rsqrtf(di);
  int s = rps[gi], d = rpd[gi];
  #pragma unroll 4
  for (int e = s; e < s+d; ++e){
    int j = gbase + adj[e];
    a += hsc[j] * rsqrtf(1.0f + (float)rpd[j]) * rdi;
  }
  float sc = a + bp[0];
  u32 b = __float_as_uint(sc);
  su[gi] = (b & 0x80000000u) ? ~b : (b | 0x80000000u);
}

// -------- per-graph top-k + pool + readout + inv --------------------------------
__launch_bounds__(512)
__global__ void topkpool(const u32* __restrict__ suG, const float* __restrict__ xin,
                         int nper, int k,
                         float* __restrict__ xp, float* __restrict__ r,
                         int* __restrict__ invG){
  __shared__ u32 su[2048];
  __shared__ int bins[256], sfx[256];
  __shared__ int slist[416];
  __shared__ int tlist[64];
  __shared__ float smx[512], ssm[512];
  __shared__ u32 spfx;
  __shared__ int srem, ssel, stie;
  int g = blockIdx.x, t = threadIdx.x;
  int gbase = g*nper;
  for (int i = t; i < nper; i += 512){
    su[i] = suG[gbase + i];
    invG[gbase + i] = -1;
  }
  if (t == 0){ spfx = 0; srem = k; ssel = 0; stie = 0; }
  __syncthreads();
  for (int pass = 0; pass < 4; ++pass){
    int shift = 24 - 8*pass;
    if (t < 256) bins[t] = 0;
    __syncthreads();
    u32 pfx = spfx; int rem = srem;
    for (int i = t; i < nper; i += 512){
      u32 u = su[i];
      if (pass == 0 || (u >> (shift+8)) == (pfx >> (shift+8)))
        atomicAdd(&bins[(u >> shift) & 255], 1);
    }
    __syncthreads();
    if (t < 256) sfx[t] = bins[t];
    __syncthreads();
    for (int off=1; off<256; off<<=1){
      int v = 0;
      if (t < 256 && t + off < 256) v = sfx[t+off];
      __syncthreads();
      if (t < 256) sfx[t] += v;
      __syncthreads();
    }
    if (t < 256){
      int above = (t == 255) ? 0 : sfx[t+1];
      if (sfx[t] >= rem && above < rem){
        spfx = pfx | ((u32)t << shift);
        srem = rem - above;
      }
    }
    __syncthreads();
  }
  u32 th = spfx;
  for (int i = t; i < nper; i += 512)
    if (su[i] > th){ int p = atomicAdd(&ssel, 1); slist[p] = i; }
  __syncthreads();
  for (int i = t; i < nper; i += 512)
    if (su[i] == th){ int q = atomicAdd(&stie, 1); if (q < 64) tlist[q] = i; }
  __syncthreads();
  if (t == 0){
    int p = ssel, need = k - p;
    if (need > 0){
      if (stie <= 64){
        for (int a = 1; a < stie; ++a){
          int v = tlist[a], b2 = a-1;
          while (b2 >= 0 && tlist[b2] > v){ tlist[b2+1] = tlist[b2]; b2--; }
          tlist[b2+1] = v;
        }
        for (int m = 0; m < need; ++m) slist[p+m] = tlist[m];
      } else {
        for (int i = 0; i < nper && p < k; ++i)
          if (su[i] == th) slist[p++] = i;
      }
    }
  }
  __syncthreads();
  int q = t >> 7, c = t & 127;
  float mxv = -3.4e38f, smv = 0.f;
  for (int j = q; j < k; j += 4){
    int li = slist[j];
    float ts = tanhf(dec_ord(su[li]));
    float vv = xin[((size_t)(gbase + li))*128 + c] * ts;
    xp[((size_t)(g*k + j))*128 + c] = vv;
    mxv = fmaxf(mxv, vv); smv += vv;
  }
  smx[t] = mxv; ssm[t] = smv;
  for (int j = t; j < k; j += 512) invG[gbase + slist[j]] = j;
  __syncthreads();
  if (t < 128){
    r[g*256 + t] = fmaxf(fmaxf(smx[t], smx[t+128]), fmaxf(smx[t+256], smx[t+384]));
    r[g*256 + 128 + t] = (ssm[t]+ssm[t+128]+ssm[t+256]+ssm[t+384]) / (float)k;
  }
}

// -------- MLP head (single block) ------------------------------------------------
__global__ void head_kernel(const float* __restrict__ r1, const float* __restrict__ r2,
                            const float* __restrict__ r3,
                            const float* __restrict__ w1, const float* __restrict__ b1,
                            const float* __restrict__ w2, const float* __restrict__ b2,
                            const float* __restrict__ w3, const float* __restrict__ b3,
                            float* __restrict__ out){
  __shared__ float hs[32][256];
  __shared__ float h1[32][128];
  __shared__ float ft[32][32];
  int t = threadIdx.x;
  for (int o = t; o < 32*256; o += 256) hs[o>>8][o&255] = r1[o]+r2[o]+r3[o];
  __syncthreads();
  for (int o = t; o < 32*128; o += 256){
    int i = o >> 7, j = o & 127;
    float a = b1[j];
    for (int c = 0; c < 256; ++c) a += hs[i][c]*w1[c*128 + j];
    h1[i][j] = fmaxf(a, 0.f);
  }
  __syncthreads();
  for (int o = t; o < 32*32; o += 256){
    int i = o >> 5, j = o & 31;
    float a = b2[j];
    for (int c = 0; c < 128; ++c) a += h1[i][c]*w2[c*32 + j];
    float v = fmaxf(a, 0.f);
    ft[i][j] = v;
    out[o] = v;
  }
  __syncthreads();
  if (t < 32){
    float a = b3[0];
    for (int c = 0; c < 32; ++c) a += ft[t][c]*w3[c];
    out[1024 + t] = a;
  }
}

extern "C" void kernel_launch(void* const* d_in, const int* in_sizes, int n_in,
                              void* d_out, int out_size, void* d_ws, size_t ws_size,
                              hipStream_t stream){
  (void)in_sizes; (void)n_in; (void)out_size; (void)ws_size;
  const float* x   = (const float*)d_in[0];
  const int* esrc  = (const int*)d_in[1];
  const int* edst  = (const int*)d_in[2];
  const float* W1l = (const float*)d_in[3];
  const float* b1l = (const float*)d_in[4];
  const float* W1r = (const float*)d_in[5];
  const float* Wp1 = (const float*)d_in[6];
  const float* bp1 = (const float*)d_in[7];
  const float* W2l = (const float*)d_in[8];
  const float* b2l = (const float*)d_in[9];
  const float* W2r = (const float*)d_in[10];
  const float* Wp2 = (const float*)d_in[11];
  const float* bp2 = (const float*)d_in[12];
  const float* W3l = (const float*)d_in[13];
  const float* b3l = (const float*)d_in[14];
  const float* W3r = (const float*)d_in[15];
  const float* Wp3 = (const float*)d_in[16];
  const float* bp3 = (const float*)d_in[17];
  const float* l1w = (const float*)d_in[18];
  const float* l1b = (const float*)d_in[19];
  const float* l2w = (const float*)d_in[20];
  const float* l2b = (const float*)d_in[21];
  const float* l3w = (const float*)d_in[22];
  const float* l3b = (const float*)d_in[23];
  float* out = (float*)d_out;

  char* ws = (char*)d_ws;
  size_t off = 0;
  auto alloc = [&](size_t bytes)->char*{
    char* p = ws + off; off = (off + bytes + 255) & ~(size_t)255; return p;
  };

  u32* mx    = (u32*)alloc(64);
  size_t z0 = off;
  int* deg1  = (int*)alloc((size_t)NN1*4);
  int* deg2  = (int*)alloc((size_t)NN2*4);
  int* deg3  = (int*)alloc((size_t)NN3*4);
  size_t zend = off;
  int* rps   = (int*)alloc((size_t)NN1*4);
  int* curB  = (int*)alloc((size_t)NN1*4);
  int* adj   = (int*)alloc((size_t)EDGESV*4);
  u16* B1h   = (u16*)alloc((size_t)KSTEP1*8192*2);
  u16* B1l   = (u16*)alloc((size_t)KSTEP1*8192*2);
  u16* B2h   = (u16*)alloc((size_t)KSTEP2*8192*2);
  u16* B2l   = (u16*)alloc((size_t)KSTEP2*8192*2);
  u16* B3h   = (u16*)alloc((size_t)KSTEP2*8192*2);
  u16* B3l   = (u16*)alloc((size_t)KSTEP2*8192*2);
  float* hlb = (float*)alloc((size_t)NN1*128*4);
  float* hrb = (float*)alloc((size_t)NN1*128*4);
  float* x1    = (float*)alloc((size_t)NN1*128*4);
  float* x2    = (float*)alloc((size_t)NN2*128*4);
  float* x3    = (float*)alloc((size_t)NN3*128*4);
  float* xp1   = (float*)alloc((size_t)NN2*128*4);
  float* xp2   = (float*)alloc((size_t)NN3*128*4);
  float* xp3   = (float*)alloc((size_t)NN4*128*4);
  float* hsc   = (float*)alloc((size_t)NN1*4);
  u32* suG     = (u32*)alloc((size_t)NN1*4);
  int* inv1G   = (int*)alloc((size_t)NN1*4);
  int* inv2G   = (int*)alloc((size_t)NN2*4);
  int* inv3G   = (int*)alloc((size_t)NN3*4);
  float* r1    = (float*)alloc((size_t)32*256*4);
  float* r2    = (float*)alloc((size_t)32*256*4);
  float* r3    = (float*)alloc((size_t)32*256*4);

  int zn = (int)((zend - z0) / 4);
  init_kernel<<<1, 64, 0, stream>>>(mx);
  fill0<<<(zn+255)/256, 256, 0, stream>>>((int*)(ws+z0), zn);
  colmax_kernel<<<256, 256, 0, stream>>>(x, mx);
  wprep_all<<<((KSTEP1+2*KSTEP2)*8192+255)/256, 256, 0, stream>>>(
      W1l, W1r, W2l, W2r, W3l, W3r, mx, B1h, B1l, B2h, B2l, B3h, B3l);

  // ===== stage 1 =====
  histf<<<EDGESV/256, 256, 0, stream>>>(esrc, edst, nullptr, nullptr, 0, N0V, deg1);
  scank<<<NB, 1024, 0, stream>>>(deg1, N0V, rps, curB);
  scatf<<<EDGESV/256, 256, 0, stream>>>(esrc, edst, nullptr, nullptr, 0, N0V, curB, adj);
  gemm_kernel<<<NN1/64, 256, 0, stream>>>(x, FEATV, FEATV, KSTEP1, B1h, B1l, hlb, hrb);
  convfin_half<<<NN1/16, 256, 0, stream>>>(hlb, hrb, rps, deg1, adj, b1l, x1, 0);
  convfin_half<<<NN1/16, 256, 0, stream>>>(hlb, hrb, rps, deg1, adj, b1l, x1, 64);
  hscgemv<<<NN1/8, 256, 0, stream>>>(x1, Wp1, hsc);
  scoreagg_w<<<dim3(N0V/256, NB), 256, 0, stream>>>(hsc, rps, deg1, adj, bp1, N0V, suG);
  topkpool<<<NB, 512, 0, stream>>>(suG, x1, N0V, KK1, xp1, r1, inv1G);

  // ===== stage 2 ===== (filter original edges through inv1)
  histf<<<EDGESV/256, 256, 0, stream>>>(esrc, edst, inv1G, nullptr, 0, KK1, deg2);
  scank<<<NB, 1024, 0, stream>>>(deg2, KK1, rps, curB);
  scatf<<<EDGESV/256, 256, 0, stream>>>(esrc, edst, inv1G, nullptr, 0, KK1, curB, adj);
  gemm_kernel<<<NN2/64, 256, 0, stream>>>(xp1, 128, 128, KSTEP2, B2h, B2l, hlb, hrb);
  convfin_w<<<NB*52, 256, 0, stream>>>(hlb, hrb, rps, deg2, adj, b2l, Wp2, x2, hsc, KK1, 52);
  scoreagg_w<<<dim3((KK1+255)/256, NB), 256, 0, stream>>>(hsc, rps, deg2, adj, bp2, KK1, suG);
  topkpool<<<NB, 512, 0, stream>>>(suG, x2, KK1, KK2, xp2, r2, inv2G);

  // ===== stage 3 ===== (filter original edges through inv1 then inv2)
  histf<<<EDGESV/256, 256, 0, stream>>>(esrc, edst, inv1G, inv2G, KK1, KK2, deg3);
  scank<<<NB, 1024, 0, stream>>>(deg3, KK2, rps, curB);
  scatf<<<EDGESV/256, 256, 0, stream>>>(esrc, edst, inv1G, inv2G, KK1, KK2, curB, adj);
  gemm_kernel<<<NN3/64, 256, 0, stream>>>(xp2, 128, 128, KSTEP2, B3h, B3l, hlb, hrb);
  convfin_w<<<NB*11, 256, 0, stream>>>(hlb, hrb, rps, deg3, adj, b3l, Wp3, x3, hsc, KK2, 11);
  scoreagg_w<<<dim3(1, NB), 256, 0, stream>>>(hsc, rps, deg3, adj, bp3, KK2, suG);
  topkpool<<<NB, 512, 0, stream>>>(suG, x3, KK2, KK3, xp3, r3, inv3G);

  // ===== head =====
  head_kernel<<<1, 256, 0, stream>>>(r1, r2, r3, l1w, l1b, l2w, l2b, l3w, l3b, out);
}

// Round 18
// 524.497 us; speedup vs baseline: 1.0252x; 1.0252x over previous
//
#include <hip/hip_runtime.h>

typedef unsigned int u32;
typedef unsigned short u16;

#define NB 32
#define N0V 2048
#define FEATV 1036
#define EDGESV (NB*N0V*16)   // 1048576
#define KK1 410
#define KK2 82
#define KK3 17
#define NN1 (NB*N0V)   // 65536
#define NN2 (NB*KK1)   // 13120
#define NN3 (NB*KK2)   // 2624
#define NN4 (NB*KK3)   // 544
#define KSTEP1 33      // ceil(1036/32)
#define KSTEP2 4       // 128/32
#define ESTR 32768     // per-graph edge region stride

typedef __bf16 bf16x8 __attribute__((ext_vector_type(8)));
typedef float f32x4 __attribute__((ext_vector_type(4)));

__device__ inline u16 f2bf(float f){
  u32 u = __float_as_uint(f);
  u32 r = (u + 0x7FFFu + ((u >> 16) & 1u)) >> 16;   // RNE
  return (u16)r;
}
__device__ inline float bf2f(u16 h){ return __uint_as_float(((u32)h) << 16); }
__device__ inline float dec_ord(u32 u){
  u32 bits = (u & 0x80000000u) ? (u ^ 0x80000000u) : ~u;
  return __uint_as_float(bits);
}
__device__ inline u16 bfbits(__bf16 b){ union{__bf16 f; u16 u;} c; c.f=b; return c.u; }
__device__ inline void cvt4c(float4 v, ushort4& h, ushort4& l){
  __bf16 h0=(__bf16)v.x, h1=(__bf16)v.y, h2=(__bf16)v.z, h3=(__bf16)v.w;
  float r0=v.x-(float)h0, r1=v.y-(float)h1, r2=v.z-(float)h2, r3=v.w-(float)h3;
  h.x=bfbits(h0); h.y=bfbits(h1); h.z=bfbits(h2); h.w=bfbits(h3);
  l.x=bfbits((__bf16)r0); l.y=bfbits((__bf16)r1);
  l.z=bfbits((__bf16)r2); l.w=bfbits((__bf16)r3);
}
__device__ inline void gload_lds16(const void* g, void* l){
  __builtin_amdgcn_global_load_lds(
      (const __attribute__((address_space(1))) unsigned int*)g,
      (__attribute__((address_space(3))) unsigned int*)l, 16, 0, 0);
}

// ---------------- zero fill (covers mx + deg buffers) ---------------------------
__global__ void fill0(int* p, int n){
  int i = blockIdx.x*256 + threadIdx.x;
  if (i < n) p[i] = 0;
}

// ---------------- column max of x[:, :12] (vectorized) -------------------------
__global__ void colmax_kernel(const float* __restrict__ x, u32* mx){
  __shared__ float sm[256];
  int t = threadIdx.x;
  int r = blockIdx.x*256 + t;          // grid 256 x 256 = NN1
  const float4* p = (const float4*)(x + (size_t)r*FEATV);
  float4 v0 = p[0], v1 = p[1], v2 = p[2];
  float m[12] = {v0.x,v0.y,v0.z,v0.w, v1.x,v1.y,v1.z,v1.w, v2.x,v2.y,v2.z,v2.w};
  for (int j=0;j<12;j++){
    sm[t] = m[j]; __syncthreads();
    for (int off=128; off>0; off>>=1){ if (t<off) sm[t]=fmaxf(sm[t],sm[t+off]); __syncthreads(); }
    if (t==0){
      u32 b = __float_as_uint(sm[0]);
      u32 u = (b & 0x80000000u) ? ~b : (b | 0x80000000u);
      atomicMax(&mx[j], u);
    }
    __syncthreads();
  }
}

// ------- build tiled B^T images for all 3 stages --------------------------------
__global__ void wprep_all(const float* __restrict__ W1l, const float* __restrict__ W1r,
                          const float* __restrict__ W2l, const float* __restrict__ W2r,
                          const float* __restrict__ W3l, const float* __restrict__ W3r,
                          const u32* __restrict__ mxo,
                          u16* __restrict__ B1h, u16* __restrict__ B1l,
                          u16* __restrict__ B2h, u16* __restrict__ B2l,
                          u16* __restrict__ B3h, u16* __restrict__ B3l){
  int idx = blockIdx.x*256 + threadIdx.x;
  const float *Wl, *Wr; u16 *oh, *ol; int K, o, scale12;
  if (idx < KSTEP1*8192){ Wl=W1l; Wr=W1r; oh=B1h; ol=B1l; K=FEATV; o=idx; scale12=1; }
  else if (idx < (KSTEP1+KSTEP2)*8192){ Wl=W2l; Wr=W2r; oh=B2h; ol=B2l; K=128; o=idx-KSTEP1*8192; scale12=0; }
  else if (idx < (KSTEP1+2*KSTEP2)*8192){ Wl=W3l; Wr=W3r; oh=B3h; ol=B3l; K=128; o=idx-(KSTEP1+KSTEP2)*8192; scale12=0; }
  else return;
  int kt = o >> 13, r13 = o & 8191;
  int khg = r13 >> 11, n = (r13 >> 3) & 255, kk8 = r13 & 7;
  int k = (kt << 5) + khg*8 + kk8;
  float v = 0.f;
  if (k < K) v = (n < 128) ? Wl[(size_t)k*128 + n] : Wr[(size_t)k*128 + (n-128)];
  if (scale12 && k < 12) v /= dec_ord(mxo[k]);
  u16 h = f2bf(v);
  oh[o] = h;
  ol[o] = f2bf(v - bf2f(h));
}

// ------- wide CSR: hist / per-graph scan / scatter (filter chain via inv1,inv2) -
__global__ void histf(const int* __restrict__ src, const int* __restrict__ dst,
                      const int* __restrict__ inv1, const int* __restrict__ inv2,
                      int np1, int nperOut, int* __restrict__ deg){
  int e = blockIdx.x*256 + threadIdx.x;
  if (e >= EDGESV) return;
  int s = src[e], d = dst[e];
  int g = d >> 11;
  int ls, ld;
  if (inv1){
    ls = inv1[s]; ld = inv1[d];
    if ((ls | ld) < 0) return;
    if (inv2){
      ls = inv2[g*np1 + ls]; ld = inv2[g*np1 + ld];
      if ((ls | ld) < 0) return;
    }
  } else { ld = d & 2047; }
  atomicAdd(&deg[g*nperOut + ld], 1);
}

__launch_bounds__(1024)
__global__ void scank(const int* __restrict__ deg, int nper,
                      int* __restrict__ rps, int* __restrict__ cur,
                      float* __restrict__ rdeg){
  __shared__ int part[1024];
  int g = blockIdx.x, t = threadIdx.x;
  int chunk = (nper + 1023) >> 10;
  int c0 = t*chunk, ss = 0;
  for (int u = 0; u < chunk; ++u){ int i = c0+u; if (i < nper) ss += deg[g*nper + i]; }
  part[t] = ss; __syncthreads();
  for (int off = 1; off < 1024; off <<= 1){
    int v = (t >= off) ? part[t-off] : 0;
    __syncthreads();
    part[t] += v;
    __syncthreads();
  }
  int run = part[t] - ss;
  for (int u = 0; u < chunk; ++u){
    int i = c0+u;
    if (i < nper){
      int dg = deg[g*nper + i];
      int pos = g*ESTR + run;
      rps[g*nper + i] = pos;
      cur[g*nper + i] = pos;
      rdeg[g*nper + i] = rsqrtf(1.0f + (float)dg);
      run += dg;
    }
  }
}

__global__ void scatf(const int* __restrict__ src, const int* __restrict__ dst,
                      const int* __restrict__ inv1, const int* __restrict__ inv2,
                      int np1, int nperOut, int* __restrict__ cur, int* __restrict__ adj){
  int e = blockIdx.x*256 + threadIdx.x;
  if (e >= EDGESV) return;
  int s = src[e], d = dst[e];
  int g = d >> 11;
  int ls, ld;
  if (inv1){
    ls = inv1[s]; ld = inv1[d];
    if ((ls | ld) < 0) return;
    if (inv2){
      ls = inv2[g*np1 + ls]; ld = inv2[g*np1 + ld];
      if ((ls | ld) < 0) return;
    }
  } else { ls = s & 2047; ld = d & 2047; }
  int p = atomicAdd(&cur[g*nperOut + ld], 1);
  adj[p] = ls;   // local src id
}

// ------- R3-structure pure GEMM (A+B LDS dbuf, counted vmcnt, 1 barrier) --------
__launch_bounds__(256, 2)
__global__ void gemm_kernel(const float* __restrict__ A, int lda,
                            int Kvalid, int Ksteps,
                            const u16* __restrict__ Bth, const u16* __restrict__ Btl,
                            float* __restrict__ hl, float* __restrict__ hr){
  __shared__ __align__(16) u16 Ah[2][2048];
  __shared__ __align__(16) u16 Al[2][2048];
  __shared__ __align__(16) u16 Bh[2][8192];
  __shared__ __align__(16) u16 Bl[2][8192];
  int tid = threadIdx.x;
  int row0 = blockIdx.x * 64;
  int w = tid >> 6, lane = tid & 63;
  int lr = lane & 15, kh = lane >> 4;

  int p0i = tid, p1i = tid + 256;
  int kg0 = p0i >> 7, rw0 = (p0i & 127) >> 1, hf0 = p0i & 1;
  int kg1 = p1i >> 7, rw1 = (p1i & 127) >> 1, hf1 = p1i & 1;
  int coff0 = kg0*8 + hf0*4, coff1 = kg1*8 + hf1*4;
  const float* pA0 = A + (size_t)(row0 + rw0)*lda + coff0;
  const float* pA1 = A + (size_t)(row0 + rw1)*lda + coff1;
  int wi0 = kg0*512 + rw0*8 + hf0*4;
  int wi1 = kg1*512 + rw1*8 + hf1*4;

  f32x4 acc[4][4];
  #pragma unroll
  for (int i=0;i<4;i++)
    #pragma unroll
    for (int j=0;j<4;j++) acc[i][j] = (f32x4){0.f,0.f,0.f,0.f};

  float4 z4 = make_float4(0.f,0.f,0.f,0.f);

#define LOADA(KT, V0, V1) { int k0_ = (KT)<<5; \
    V0 = (k0_ + coff0 < Kvalid) ? *(const float4*)(pA0 + k0_) : z4; \
    V1 = (k0_ + coff1 < Kvalid) ? *(const float4*)(pA1 + k0_) : z4; }

#define ISSUEB(KT, BUF) { size_t tb_ = (size_t)(KT)*8192; \
    _Pragma("unroll") \
    for (int j_=0;j_<4;j_++){ int o_ = j_*2048 + w*512; \
      gload_lds16(Bth + tb_ + o_ + lane*8, &Bh[BUF][o_]); \
      gload_lds16(Btl + tb_ + o_ + lane*8, &Bl[BUF][o_]); } }

#define CVTWRITE(V0, V1, BUF) { ushort4 h_, l_; \
    cvt4c(V0, h_, l_); *(ushort4*)&Ah[BUF][wi0] = h_; *(ushort4*)&Al[BUF][wi0] = l_; \
    cvt4c(V1, h_, l_); *(ushort4*)&Ah[BUF][wi1] = h_; *(ushort4*)&Al[BUF][wi1] = l_; }

  // ---- prologue ----
  float4 a0, a1, pp0, pp1;
  LOADA(0, a0, a1);
  ISSUEB(0, 0);
  LOADA(1, pp0, pp1);
  CVTWRITE(a0, a1, 0);
  asm volatile("s_waitcnt lgkmcnt(0)" ::: "memory");
  asm volatile("s_waitcnt vmcnt(2)" ::: "memory");
  __builtin_amdgcn_s_barrier();

  for (int kt = 0; kt < Ksteps; ++kt){
    int cur = kt & 1, nxt = cur ^ 1;
    if (kt+1 < Ksteps) ISSUEB(kt+1, nxt);
    float4 n0 = z4, n1 = z4;
    if (kt+2 < Ksteps) LOADA(kt+2, n0, n1);
    if (kt+2 < Ksteps)      asm volatile("s_waitcnt vmcnt(12)" ::: "memory");
    else if (kt+1 < Ksteps) asm volatile("s_waitcnt vmcnt(10)" ::: "memory");
    else                    asm volatile("s_waitcnt vmcnt(0)"  ::: "memory");

    bf16x8 fah[4], fal[4], fbh[4], fbl[4];
    #pragma unroll
    for (int mi=0;mi<4;mi++){
      int idx = kh*512 + (mi*16 + lr)*8;
      fah[mi] = *(const bf16x8*)&Ah[cur][idx];
      fal[mi] = *(const bf16x8*)&Al[cur][idx];
    }
    #pragma unroll
    for (int ni=0;ni<4;ni++){
      int idx = kh*2048 + (w*64 + ni*16 + lr)*8;
      fbh[ni] = *(const bf16x8*)&Bh[cur][idx];
      fbl[ni] = *(const bf16x8*)&Bl[cur][idx];
    }
    if (kt+1 < Ksteps) CVTWRITE(pp0, pp1, nxt);
    asm volatile("s_waitcnt lgkmcnt(0)" ::: "memory");
    __builtin_amdgcn_sched_barrier(0);
    __builtin_amdgcn_s_setprio(1);
    #pragma unroll
    for (int mi=0;mi<4;mi++)
      #pragma unroll
      for (int ni=0;ni<4;ni++){
        acc[mi][ni] = __builtin_amdgcn_mfma_f32_16x16x32_bf16(fah[mi], fbh[ni], acc[mi][ni], 0,0,0);
        acc[mi][ni] = __builtin_amdgcn_mfma_f32_16x16x32_bf16(fah[mi], fbl[ni], acc[mi][ni], 0,0,0);
        acc[mi][ni] = __builtin_amdgcn_mfma_f32_16x16x32_bf16(fal[mi], fbh[ni], acc[mi][ni], 0,0,0);
      }
    __builtin_amdgcn_s_setprio(0);
    pp0 = n0; pp1 = n1;
    __builtin_amdgcn_s_barrier();
  }
#undef LOADA
#undef ISSUEB
#undef CVTWRITE
  // epilogue: split C cols 0..127 -> hl, 128..255 -> hr
  float* dst = (w < 2) ? hl : hr;
  #pragma unroll
  for (int mi=0;mi<4;mi++)
    #pragma unroll
    for (int j=0;j<4;j++){
      int row = row0 + mi*16 + kh*4 + j;
      #pragma unroll
      for (int ni=0;ni<4;ni++){
        int ch = (w*64 + ni*16 + lr) & 127;
        dst[(size_t)row*128 + ch] = acc[mi][ni][j];
      }
    }
}

// -------- SAGE finalize + score GEMV: batch-8 neighbor prefetch -----------------
__global__ void convfin_w(const float* __restrict__ hl, const float* __restrict__ hr,
                          const int* __restrict__ rps,
                          const int* __restrict__ rpd, const int* __restrict__ adj,
                          const float* __restrict__ bl, const float* __restrict__ Wp,
                          float* __restrict__ xout, float* __restrict__ hsc,
                          int nper, int bpg, int xcdMap){
  int b = blockIdx.x, t = threadIdx.x;
  int g, slot;
  if (xcdMap){ int xcd = b & 7, idx = b >> 3; g = xcd + 8*(idx >> 8); slot = idx & 255; }
  else { g = b / bpg; slot = b - g*bpg; }
  int wv = t >> 6, lane = t & 63;
  int sub = lane >> 5, l32 = lane & 31;
  int i = slot*8 + wv*2 + sub;
  if (i >= nper) return;
  int gbase = g*nper;
  int gi = gbase + i;
  int s = rps[gi], d = rpd[gi];
  const int* ap = adj + s;
  float4 a = make_float4(0.f,0.f,0.f,0.f);
  int e = 0;
  for (; e + 8 <= d; e += 8){
    int j0=ap[e],j1=ap[e+1],j2=ap[e+2],j3=ap[e+3];
    int j4=ap[e+4],j5=ap[e+5],j6=ap[e+6],j7=ap[e+7];
    float4 v0 = *(const float4*)(hl + (size_t)(gbase+j0)*128 + l32*4);
    float4 v1 = *(const float4*)(hl + (size_t)(gbase+j1)*128 + l32*4);
    float4 v2 = *(const float4*)(hl + (size_t)(gbase+j2)*128 + l32*4);
    float4 v3 = *(const float4*)(hl + (size_t)(gbase+j3)*128 + l32*4);
    float4 v4 = *(const float4*)(hl + (size_t)(gbase+j4)*128 + l32*4);
    float4 v5 = *(const float4*)(hl + (size_t)(gbase+j5)*128 + l32*4);
    float4 v6 = *(const float4*)(hl + (size_t)(gbase+j6)*128 + l32*4);
    float4 v7 = *(const float4*)(hl + (size_t)(gbase+j7)*128 + l32*4);
    a.x += v0.x+v1.x+v2.x+v3.x+v4.x+v5.x+v6.x+v7.x;
    a.y += v0.y+v1.y+v2.y+v3.y+v4.y+v5.y+v6.y+v7.y;
    a.z += v0.z+v1.z+v2.z+v3.z+v4.z+v5.z+v6.z+v7.z;
    a.w += v0.w+v1.w+v2.w+v3.w+v4.w+v5.w+v6.w+v7.w;
  }
  for (; e < d; ++e){
    float4 hj = *(const float4*)(hl + (size_t)(gbase + ap[e])*128 + l32*4);
    a.x += hj.x; a.y += hj.y; a.z += hj.z; a.w += hj.w;
  }
  float invc = 1.0f / fmaxf((float)d, 1.0f);
  float4 hrv = *(const float4*)(hr + (size_t)gi*128 + l32*4);
  float4 bb = *(const float4*)(bl + l32*4);
  float4 o;
  o.x = fmaxf(a.x*invc + bb.x + hrv.x, 0.f);
  o.y = fmaxf(a.y*invc + bb.y + hrv.y, 0.f);
  o.z = fmaxf(a.z*invc + bb.z + hrv.z, 0.f);
  o.w = fmaxf(a.w*invc + bb.w + hrv.w, 0.f);
  *(float4*)(xout + (size_t)gi*128 + l32*4) = o;
  float4 wp = *(const float4*)(Wp + l32*4);
  float v = o.x*wp.x + o.y*wp.y + o.z*wp.z + o.w*wp.w;
  #pragma unroll
  for (int m = 16; m > 0; m >>= 1) v += __shfl_xor(v, m);
  if (l32 == 0) hsc[gi] = v;
}

// -------- GCN score (2D grid: y=graph), rdeg precomputed ------------------------
__global__ void scoreagg_w(const float* __restrict__ hsc, const int* __restrict__ rps,
                           const int* __restrict__ rpd, const float* __restrict__ rdeg,
                           const int* __restrict__ adj,
                           const float* __restrict__ bp, int nper,
                           u32* __restrict__ su){
  int g = blockIdx.y;
  int i = blockIdx.x*256 + threadIdx.x;
  if (i >= nper) return;
  int gbase = g*nper;
  int gi = gbase + i;
  float di = 1.0f + (float)rpd[gi];
  float a = hsc[gi] / di;
  float rdi = rdeg[gi];
  int s = rps[gi], d = rpd[gi];
  #pragma unroll 4
  for (int e = s; e < s+d; ++e){
    int j = gbase + adj[e];
    a += hsc[j] * rdeg[j] * rdi;
  }
  float sc = a + bp[0];
  u32 b = __float_as_uint(sc);
  su[gi] = (b & 0x80000000u) ? ~b : (b | 0x80000000u);
}

// -------- per-graph top-k + pool + readout + inv --------------------------------
__launch_bounds__(512)
__global__ void topkpool(const u32* __restrict__ suG, const float* __restrict__ xin,
                         int nper, int k,
                         float* __restrict__ xp, float* __restrict__ r,
                         int* __restrict__ invG){
  __shared__ u32 su[2048];
  __shared__ int bins[256], sfx[256];
  __shared__ int slist[416];
  __shared__ int tlist[64];
  __shared__ float smx[512], ssm[512];
  __shared__ u32 spfx;
  __shared__ int srem, ssel, stie;
  int g = blockIdx.x, t = threadIdx.x;
  int gbase = g*nper;
  for (int i = t; i < nper; i += 512){
    su[i] = suG[gbase + i];
    invG[gbase + i] = -1;
  }
  if (t == 0){ spfx = 0; srem = k; ssel = 0; stie = 0; }
  __syncthreads();
  for (int pass = 0; pass < 4; ++pass){
    int shift = 24 - 8*pass;
    if (t < 256) bins[t] = 0;
    __syncthreads();
    u32 pfx = spfx; int rem = srem;
    for (int i = t; i < nper; i += 512){
      u32 u = su[i];
      if (pass == 0 || (u >> (shift+8)) == (pfx >> (shift+8)))
        atomicAdd(&bins[(u >> shift) & 255], 1);
    }
    __syncthreads();
    if (t < 256) sfx[t] = bins[t];
    __syncthreads();
    for (int off=1; off<256; off<<=1){
      int v = 0;
      if (t < 256 && t + off < 256) v = sfx[t+off];
      __syncthreads();
      if (t < 256) sfx[t] += v;
      __syncthreads();
    }
    if (t < 256){
      int above = (t == 255) ? 0 : sfx[t+1];
      if (sfx[t] >= rem && above < rem){
        spfx = pfx | ((u32)t << shift);
        srem = rem - above;
      }
    }
    __syncthreads();
  }
  u32 th = spfx;
  for (int i = t; i < nper; i += 512)
    if (su[i] > th){ int p = atomicAdd(&ssel, 1); slist[p] = i; }
  __syncthreads();
  for (int i = t; i < nper; i += 512)
    if (su[i] == th){ int q = atomicAdd(&stie, 1); if (q < 64) tlist[q] = i; }
  __syncthreads();
  if (t == 0){
    int p = ssel, need = k - p;
    if (need > 0){
      if (stie <= 64){
        for (int a = 1; a < stie; ++a){
          int v = tlist[a], b2 = a-1;
          while (b2 >= 0 && tlist[b2] > v){ tlist[b2+1] = tlist[b2]; b2--; }
          tlist[b2+1] = v;
        }
        for (int m = 0; m < need; ++m) slist[p+m] = tlist[m];
      } else {
        for (int i = 0; i < nper && p < k; ++i)
          if (su[i] == th) slist[p++] = i;
      }
    }
  }
  __syncthreads();
  int q = t >> 7, c = t & 127;
  float mxv = -3.4e38f, smv = 0.f;
  for (int j = q; j < k; j += 4){
    int li = slist[j];
    float ts = tanhf(dec_ord(su[li]));
    float vv = xin[((size_t)(gbase + li))*128 + c] * ts;
    xp[((size_t)(g*k + j))*128 + c] = vv;
    mxv = fmaxf(mxv, vv); smv += vv;
  }
  smx[t] = mxv; ssm[t] = smv;
  for (int j = t; j < k; j += 512) invG[gbase + slist[j]] = j;
  __syncthreads();
  if (t < 128){
    r[g*256 + t] = fmaxf(fmaxf(smx[t], smx[t+128]), fmaxf(smx[t+256], smx[t+384]));
    r[g*256 + 128 + t] = (ssm[t]+ssm[t+128]+ssm[t+256]+ssm[t+384]) / (float)k;
  }
}

// -------- MLP head (single block) ------------------------------------------------
__global__ void head_kernel(const float* __restrict__ r1, const float* __restrict__ r2,
                            const float* __restrict__ r3,
                            const float* __restrict__ w1, const float* __restrict__ b1,
                            const float* __restrict__ w2, const float* __restrict__ b2,
                            const float* __restrict__ w3, const float* __restrict__ b3,
                            float* __restrict__ out){
  __shared__ float hs[32][256];
  __shared__ float h1[32][128];
  __shared__ float ft[32][32];
  int t = threadIdx.x;
  for (int o = t; o < 32*256; o += 256) hs[o>>8][o&255] = r1[o]+r2[o]+r3[o];
  __syncthreads();
  for (int o = t; o < 32*128; o += 256){
    int i = o >> 7, j = o & 127;
    float a = b1[j];
    for (int c = 0; c < 256; ++c) a += hs[i][c]*w1[c*128 + j];
    h1[i][j] = fmaxf(a, 0.f);
  }
  __syncthreads();
  for (int o = t; o < 32*32; o += 256){
    int i = o >> 5, j = o & 31;
    float a = b2[j];
    for (int c = 0; c < 128; ++c) a += h1[i][c]*w2[c*32 + j];
    float v = fmaxf(a, 0.f);
    ft[i][j] = v;
    out[o] = v;
  }
  __syncthreads();
  if (t < 32){
    float a = b3[0];
    for (int c = 0; c < 32; ++c) a += ft[t][c]*w3[c];
    out[1024 + t] = a;
  }
}

extern "C" void kernel_launch(void* const* d_in, const int* in_sizes, int n_in,
                              void* d_out, int out_size, void* d_ws, size_t ws_size,
                              hipStream_t stream){
  (void)in_sizes; (void)n_in; (void)out_size; (void)ws_size;
  const float* x   = (const float*)d_in[0];
  const int* esrc  = (const int*)d_in[1];
  const int* edst  = (const int*)d_in[2];
  const float* W1l = (const float*)d_in[3];
  const float* b1l = (const float*)d_in[4];
  const float* W1r = (const float*)d_in[5];
  const float* Wp1 = (const float*)d_in[6];
  const float* bp1 = (const float*)d_in[7];
  const float* W2l = (const float*)d_in[8];
  const float* b2l = (const float*)d_in[9];
  const float* W2r = (const float*)d_in[10];
  const float* Wp2 = (const float*)d_in[11];
  const float* bp2 = (const float*)d_in[12];
  const float* W3l = (const float*)d_in[13];
  const float* b3l = (const float*)d_in[14];
  const float* W3r = (const float*)d_in[15];
  const float* Wp3 = (const float*)d_in[16];
  const float* bp3 = (const float*)d_in[17];
  const float* l1w = (const float*)d_in[18];
  const float* l1b = (const float*)d_in[19];
  const float* l2w = (const float*)d_in[20];
  const float* l2b = (const float*)d_in[21];
  const float* l3w = (const float*)d_in[22];
  const float* l3b = (const float*)d_in[23];
  float* out = (float*)d_out;

  char* ws = (char*)d_ws;
  size_t off = 0;
  auto alloc = [&](size_t bytes)->char*{
    char* p = ws + off; off = (off + bytes + 255) & ~(size_t)255; return p;
  };

  // zero group: mx + deg buffers (one fill kernel)
  size_t z0 = off;
  u32* mx    = (u32*)alloc(64);
  int* deg1  = (int*)alloc((size_t)NN1*4);
  int* deg2  = (int*)alloc((size_t)NN2*4);
  int* deg3  = (int*)alloc((size_t)NN3*4);
  size_t zend = off;
  int* rps   = (int*)alloc((size_t)NN1*4);
  int* curB  = (int*)alloc((size_t)NN1*4);
  float* rdeg= (float*)alloc((size_t)NN1*4);
  int* adj   = (int*)alloc((size_t)EDGESV*4);
  u16* B1h   = (u16*)alloc((size_t)KSTEP1*8192*2);
  u16* B1l   = (u16*)alloc((size_t)KSTEP1*8192*2);
  u16* B2h   = (u16*)alloc((size_t)KSTEP2*8192*2);
  u16* B2l   = (u16*)alloc((size_t)KSTEP2*8192*2);
  u16* B3h   = (u16*)alloc((size_t)KSTEP2*8192*2);
  u16* B3l   = (u16*)alloc((size_t)KSTEP2*8192*2);
  float* hlb = (float*)alloc((size_t)NN1*128*4);
  float* hrb = (float*)alloc((size_t)NN1*128*4);
  float* x1    = (float*)alloc((size_t)NN1*128*4);
  float* x2    = (float*)alloc((size_t)NN2*128*4);
  float* x3    = (float*)alloc((size_t)NN3*128*4);
  float* xp1   = (float*)alloc((size_t)NN2*128*4);
  float* xp2   = (float*)alloc((size_t)NN3*128*4);
  float* xp3   = (float*)alloc((size_t)NN4*128*4);
  float* hsc   = (float*)alloc((size_t)NN1*4);
  u32* suG     = (u32*)alloc((size_t)NN1*4);
  int* inv1G   = (int*)alloc((size_t)NN1*4);
  int* inv2G   = (int*)alloc((size_t)NN2*4);
  int* inv3G   = (int*)alloc((size_t)NN3*4);
  float* r1    = (float*)alloc((size_t)32*256*4);
  float* r2    = (float*)alloc((size_t)32*256*4);
  float* r3    = (float*)alloc((size_t)32*256*4);

  int zn = (int)((zend - z0) / 4);
  fill0<<<(zn+255)/256, 256, 0, stream>>>((int*)(ws+z0), zn);
  colmax_kernel<<<256, 256, 0, stream>>>(x, mx);
  wprep_all<<<((KSTEP1+2*KSTEP2)*8192+255)/256, 256, 0, stream>>>(
      W1l, W1r, W2l, W2r, W3l, W3r, mx, B1h, B1l, B2h, B2l, B3h, B3l);

  // ===== stage 1 =====
  histf<<<EDGESV/256, 256, 0, stream>>>(esrc, edst, nullptr, nullptr, 0, N0V, deg1);
  scank<<<NB, 1024, 0, stream>>>(deg1, N0V, rps, curB, rdeg);
  scatf<<<EDGESV/256, 256, 0, stream>>>(esrc, edst, nullptr, nullptr, 0, N0V, curB, adj);
  gemm_kernel<<<NN1/64, 256, 0, stream>>>(x, FEATV, FEATV, KSTEP1, B1h, B1l, hlb, hrb);
  convfin_w<<<NN1/8, 256, 0, stream>>>(hlb, hrb, rps, deg1, adj, b1l, Wp1, x1, hsc, N0V, 256, 1);
  scoreagg_w<<<dim3(N0V/256, NB), 256, 0, stream>>>(hsc, rps, deg1, rdeg, adj, bp1, N0V, suG);
  topkpool<<<NB, 512, 0, stream>>>(suG, x1, N0V, KK1, xp1, r1, inv1G);

  // ===== stage 2 ===== (filter original edges through inv1)
  histf<<<EDGESV/256, 256, 0, stream>>>(esrc, edst, inv1G, nullptr, 0, KK1, deg2);
  scank<<<NB, 1024, 0, stream>>>(deg2, KK1, rps, curB, rdeg);
  scatf<<<EDGESV/256, 256, 0, stream>>>(esrc, edst, inv1G, nullptr, 0, KK1, curB, adj);
  gemm_kernel<<<NN2/64, 256, 0, stream>>>(xp1, 128, 128, KSTEP2, B2h, B2l, hlb, hrb);
  convfin_w<<<NB*52, 256, 0, stream>>>(hlb, hrb, rps, deg2, adj, b2l, Wp2, x2, hsc, KK1, 52, 0);
  scoreagg_w<<<dim3((KK1+255)/256, NB), 256, 0, stream>>>(hsc, rps, deg2, rdeg, adj, bp2, KK1, suG);
  topkpool<<<NB, 512, 0, stream>>>(suG, x2, KK1, KK2, xp2, r2, inv2G);

  // ===== stage 3 ===== (filter original edges through inv1 then inv2)
  histf<<<EDGESV/256, 256, 0, stream>>>(esrc, edst, inv1G, inv2G, KK1, KK2, deg3);
  scank<<<NB, 1024, 0, stream>>>(deg3, KK2, rps, curB, rdeg);
  scatf<<<EDGESV/256, 256, 0, stream>>>(esrc, edst, inv1G, inv2G, KK1, KK2, curB, adj);
  gemm_kernel<<<NN3/64, 256, 0, stream>>>(xp2, 128, 128, KSTEP2, B3h, B3l, hlb, hrb);
  convfin_w<<<NB*11, 256, 0, stream>>>(hlb, hrb, rps, deg3, adj, b3l, Wp3, x3, hsc, KK2, 11, 0);
  scoreagg_w<<<dim3(1, NB), 256, 0, stream>>>(hsc, rps, deg3, rdeg, adj, bp3, KK2, suG);
  topkpool<<<NB, 512, 0, stream>>>(suG, x3, KK2, KK3, xp3, r3, inv3G);

  // ===== head =====
  head_kernel<<<1, 256, 0, stream>>>(r1, r2, r3, l1w, l1b, l2w, l2b, l3w, l3b, out);
}